// Round 11
// baseline (983.350 us; speedup 1.0000x reference)
//
#include <hip/hip_runtime.h>
#include <hip/hip_bf16.h>

#define N_NODES 100000
#define N_EDGES 600000
#define DIN 64
#define DE 8
#define D 128
#define TWO_D 256
#define L_LAYERS 5
#define BN_EPS 1e-5f

#define SCAN_B 256
#define SCAN_NB ((N_NODES + SCAN_B - 1) / SCAN_B)   // 391

typedef unsigned short u16;
typedef unsigned int u32;
typedef __attribute__((ext_vector_type(8))) short short8;   // 8 bf16 MFMA A/B frag
typedef __attribute__((ext_vector_type(4))) float f32x4;    // MFMA C/D frag / native float4

__device__ inline u16 f2bf(float f) {
    __hip_bfloat16 h = __float2bfloat16(f);
    return *reinterpret_cast<u16*>(&h);
}
__device__ inline float bf2f(u16 u) {
    union { u32 i; float f; } v;
    v.i = ((u32)u) << 16;
    return v.f;
}
// packed pair {lo: h[c], hi: h[c+64]} in one u32
__device__ inline float bfLo(u32 v) {
    union { u32 i; float f; } u;
    u.i = v << 16;
    return u.f;
}
__device__ inline float bfHi(u32 v) {
    union { u32 i; float f; } u;
    u.i = v & 0xffff0000u;
    return u.f;
}
__device__ inline u32 packbf(float a, float b) {
    return (u32)f2bf(a) | ((u32)f2bf(b) << 16);
}

// ---------------- CSR build ----------------

__global__ void hist_kernel(const int* __restrict__ dst, int* __restrict__ deg) {
    int i = blockIdx.x * blockDim.x + threadIdx.x;
    if (i < N_EDGES) atomicAdd(&deg[dst[i]], 1);
}

__global__ void scan_partial_kernel(const int* __restrict__ deg, int* __restrict__ blocksum) {
    __shared__ int red[SCAN_B];
    int tid = threadIdx.x;
    int i = blockIdx.x * SCAN_B + tid;
    red[tid] = (i < N_NODES) ? deg[i] : 0;
    __syncthreads();
    for (int off = SCAN_B / 2; off > 0; off >>= 1) {
        if (tid < off) red[tid] += red[tid + off];
        __syncthreads();
    }
    if (tid == 0) blocksum[blockIdx.x] = red[0];
}

__global__ void scan_blocks_kernel(int* __restrict__ blocksum, int* __restrict__ total) {
    __shared__ int sh[512];
    int tid = threadIdx.x;
    int v = (tid < SCAN_NB) ? blocksum[tid] : 0;
    sh[tid] = v;
    __syncthreads();
    for (int off = 1; off < 512; off <<= 1) {
        int w = (tid >= off) ? sh[tid - off] : 0;
        __syncthreads();
        sh[tid] += w;
        __syncthreads();
    }
    if (tid < SCAN_NB) blocksum[tid] = sh[tid] - v;  // exclusive
    if (tid == 511) *total = sh[511];
}

__global__ void scan_apply_kernel(const int* __restrict__ deg, const int* __restrict__ blocksum,
                                  const int* __restrict__ total, int* __restrict__ rowptr,
                                  int* __restrict__ cursor) {
    __shared__ int sh[SCAN_B];
    int tid = threadIdx.x;
    int i = blockIdx.x * SCAN_B + tid;
    int v = (i < N_NODES) ? deg[i] : 0;
    sh[tid] = v;
    __syncthreads();
    for (int off = 1; off < SCAN_B; off <<= 1) {
        int w = (tid >= off) ? sh[tid - off] : 0;
        __syncthreads();
        sh[tid] += w;
        __syncthreads();
    }
    if (i < N_NODES) {
        int p = blocksum[blockIdx.x] + sh[tid] - v;  // exclusive prefix
        rowptr[i] = p;
        cursor[i] = p;
    }
    if (i == N_NODES - 1) rowptr[N_NODES] = *total;
}

// scatter: csr_src[p] = src  AND  ea_perm[p] = ea[edge]  (edge attrs in CSR order
// -> front's ea reads become sequential; only the ub gather stays random)
__global__ void scatter_kernel(const int* __restrict__ dst, const int* __restrict__ src,
                               const float* __restrict__ ea, int* __restrict__ cursor,
                               int* __restrict__ csr_src, float4* __restrict__ eap) {
    int i = blockIdx.x * blockDim.x + threadIdx.x;
    if (i < N_EDGES) {
        int d = dst[i];
        int p = atomicAdd(&cursor[d], 1);
        csr_src[p] = src[i];
        const float4* s = (const float4*)(ea + (size_t)i * DE);
        eap[(size_t)p * 2] = s[0];
        eap[(size_t)p * 2 + 1] = s[1];
    }
}

// ---------------- W pre-transpose ----------------
// w1t: fp32 [L][128][256] -> bf16 [L][256][128]   (GEMM1 B, [n][k])
// w2t: fp32 [L][256][128] -> bf16 [L][128][256]   (GEMM2 B, [n][k])
// wnh/wnl: fp32 [64][128] -> bf16 hi/lo [128][64] (encoder B, [n][k], split for ~fp32 acc)

__global__ void prep_w_kernel(const float* __restrict__ W1, const float* __restrict__ W2,
                              const float* __restrict__ Wn, u16* __restrict__ w1t,
                              u16* __restrict__ w2t, u16* __restrict__ wnh,
                              u16* __restrict__ wnl) {
    int idx = blockIdx.x * blockDim.x + threadIdx.x;
    const int T1 = L_LAYERS * TWO_D * D;   // 163840
    if (idx < T1) {
        int l = idx / (TWO_D * D);
        int rem = idx - l * (TWO_D * D);
        int n = rem >> 7;      // 0..255
        int k = rem & 127;     // 0..127
        w1t[idx] = f2bf(W1[((size_t)l * D + k) * TWO_D + n]);
    } else if (idx < 2 * T1) {
        int jdx = idx - T1;
        int l = jdx / (D * TWO_D);
        int rem = jdx - l * (D * TWO_D);
        int n = rem >> 8;      // 0..127
        int k = rem & 255;     // 0..255
        w2t[jdx] = f2bf(W2[((size_t)l * TWO_D + k) * D + n]);
    } else if (idx < 2 * T1 + D * DIN) {
        int r = idx - 2 * T1;
        int n = r >> 6;        // 0..127
        int k = r & 63;        // 0..63
        float v = Wn[(size_t)k * D + n];
        u16 hi = f2bf(v);
        wnh[r] = hi;
        wnl[r] = f2bf(v - bf2f(hi));
    }
}

// ---------------- node encoder (MFMA): ub = pack_bf16(x @ Wn + bn0) ----------------

__launch_bounds__(256, 4)
__global__ void encoder_kernel(const float* __restrict__ x, const u16* __restrict__ wnh,
                               const u16* __restrict__ wnl, const float* __restrict__ bn0,
                               u32* __restrict__ ub) {
    __shared__ __align__(16) u16 ENC[2 * 64 * 72];   // Ah, Al: 18.4 KB
    u16* Ah = ENC;
    u16* Al = ENC + 64 * 72;

    int tid = threadIdx.x;
    int row0 = blockIdx.x * 64;

    // stage x [64 rows][64 k] fp32 -> hi/lo bf16
#pragma unroll
    for (int p = 0; p < 4; p++) {
        int idx = tid + p * 256;
        int row = idx >> 4, c4 = (idx & 15) * 4;
        f32x4 v = (f32x4){0.f, 0.f, 0.f, 0.f};
        if (row0 + row < N_NODES)
            v = *(const f32x4*)(x + (size_t)(row0 + row) * DIN + c4);
        u16 hi4[4], lo4[4];
#pragma unroll
        for (int i = 0; i < 4; i++) {
            u16 hi = f2bf(v[i]);
            hi4[i] = hi;
            lo4[i] = f2bf(v[i] - bf2f(hi));
        }
        *(uint2*)(&Ah[row * 72 + c4]) = *(const uint2*)hi4;
        *(uint2*)(&Al[row * 72 + c4]) = *(const uint2*)lo4;
    }
    __syncthreads();

    int lane = tid & 63, wave = tid >> 6;
    int m16 = lane & 15, kq = lane >> 4;
    f32x4 acc[4][2];
#pragma unroll
    for (int i = 0; i < 4; i++)
#pragma unroll
        for (int c = 0; c < 2; c++) acc[i][c] = (f32x4){0.f, 0.f, 0.f, 0.f};

#pragma unroll
    for (int ks = 0; ks < 2; ks++) {
        int k0 = ks * 32 + kq * 8;
        short8 Bh[2], Bl[2];
#pragma unroll
        for (int ct = 0; ct < 2; ct++) {
            int col = ct * 64 + wave * 16 + m16;
            Bh[ct] = *(const short8*)(wnh + (size_t)col * DIN + k0);
            Bl[ct] = *(const short8*)(wnl + (size_t)col * DIN + k0);
        }
        short8 ah[4], al[4];
#pragma unroll
        for (int rt = 0; rt < 4; rt++) {
            ah[rt] = *(const short8*)(&Ah[(rt * 16 + m16) * 72 + k0]);
            al[rt] = *(const short8*)(&Al[(rt * 16 + m16) * 72 + k0]);
        }
#pragma unroll
        for (int rt = 0; rt < 4; rt++)
#pragma unroll
            for (int ct = 0; ct < 2; ct++) {
                acc[rt][ct] = __builtin_amdgcn_mfma_f32_16x16x32_bf16(ah[rt], Bh[ct],
                                                                     acc[rt][ct], 0, 0, 0);
                acc[rt][ct] = __builtin_amdgcn_mfma_f32_16x16x32_bf16(al[rt], Bh[ct],
                                                                     acc[rt][ct], 0, 0, 0);
                acc[rt][ct] = __builtin_amdgcn_mfma_f32_16x16x32_bf16(ah[rt], Bl[ct],
                                                                     acc[rt][ct], 0, 0, 0);
            }
    }

    // epilogue: bias, packed bf16-pair store (cols c and c+64)
    int c = wave * 16 + m16;
    float b0 = bn0[c], b1v = bn0[64 + c];
#pragma unroll
    for (int rt = 0; rt < 4; rt++) {
#pragma unroll
        for (int rr = 0; rr < 4; rr++) {
            int row = row0 + rt * 16 + kq * 4 + rr;
            if (row < N_NODES)
                ub[(size_t)row * 64 + c] = packbf(acc[rt][0][rr] + b0,
                                                  acc[rt][1][rr] + b1v);
        }
    }
}

// ---------------- front: fused [BN2-apply ∘ gather ∘ GEMM1] ----------------
// 256-thread / 32-row tiles: 4 waves x 8 rows. LDS ~19.6 KB.
// Edge state wave-uniform (readfirstlane -> scalar loads / branches).
// ea_perm is in CSR order -> ea reads are SEQUENTIAL (L2-streamed); the packed
// ub gather (4 B/edge/lane) is the only random load. 2-chunk ping-pong.

__launch_bounds__(256, 3)
__global__ void front_kernel(const u32* __restrict__ ub, const float4* __restrict__ eap,
                             const int* __restrict__ rowptr_g, const int* __restrict__ csr_src,
                             const float* __restrict__ We, const float* __restrict__ bee,
                             const float* __restrict__ epsArr, int layer, int use_aff,
                             const float* __restrict__ aff2a, const float* __restrict__ aff2b,
                             const u16* __restrict__ w1t, const float* __restrict__ b1,
                             float* __restrict__ t, float* __restrict__ s1,
                             float* __restrict__ s1sq) {
    __shared__ __align__(16) u16 UNI[2 * 32 * 136];   // Ah, Al (32 rows each): 17 KB
    __shared__ float sred[512];
    __shared__ int rp[36];

    u16* Ah = UNI;
    u16* Al = UNI + 32 * 136;

    int tid = threadIdx.x;
    int row0 = blockIdx.x * 32;

    if (tid < 33) {
        int g = row0 + tid;
        rp[tid] = rowptr_g[(g < N_NODES) ? g : N_NODES];
    }
    sred[tid] = 0.f;
    sred[256 + tid] = 0.f;
    __syncthreads();

    int lane = tid & 63, wave = tid >> 6;
    int j = lane;
    float epsv = 1.0f + epsArr[layer];

    // hoisted layer params (registers, loaded once; L2-hot)
    float WeR[16];   // WeR[2k] = We[k][j], WeR[2k+1] = We[k][j+64]
#pragma unroll
    for (int k = 0; k < 8; k++) {
        WeR[2 * k] = We[k * D + j];
        WeR[2 * k + 1] = We[k * D + 64 + j];
    }
    float bee0 = bee[j], bee1 = bee[64 + j];
    float fA0 = 0.f, fA1 = 0.f, fB0 = 0.f, fB1 = 0.f;
    if (use_aff) {
        fA0 = aff2a[j]; fA1 = aff2a[64 + j];
        fB0 = aff2b[j]; fB1 = aff2b[64 + j];
    }

    // ---- streaming gather: scalar-ified control, 2-chunk ping-pong ----
    {
        int wbeg = wave * 8, wend = wbeg + 8;
        int pbeg = __builtin_amdgcn_readfirstlane(rp[wbeg]);
        int pend = __builtin_amdgcn_readfirstlane(rp[wend]);
        int rloc = wbeg;
        int p1c = __builtin_amdgcn_readfirstlane(rp[wbeg + 1]);
        float acc_a = 0.f, acc_b = 0.f;
        float rCa = 0.f, rCb = 0.f, rNa = 0.f, rNb = 0.f;
        {
            int n0 = row0 + wbeg;
            if (n0 < N_NODES) {
                u32 r0 = ub[(size_t)n0 * 64 + j];
                rCa = bfLo(r0); rCb = bfHi(r0);
            }
            int n1 = n0 + 1;
            if (n1 < N_NODES) {
                u32 r1 = ub[(size_t)n1 * 64 + j];
                rNa = bfLo(r1); rNb = bfHi(r1);
            }
        }

        auto flushRow = [&]() {
            float oa = rCa, ob = rCb;
            if (use_aff) {
                oa = fmaxf(fmaf(fA0, oa, fB0), 0.f);
                ob = fmaxf(fmaf(fA1, ob, fB1), 0.f);
            }
            float za = fmaf(epsv, oa, acc_a);
            float zb = fmaf(epsv, ob, acc_b);
            u16 ha = f2bf(za), hb = f2bf(zb);
            Ah[rloc * 136 + j] = ha;
            Ah[rloc * 136 + 64 + j] = hb;
            Al[rloc * 136 + j] = f2bf(za - bf2f(ha));
            Al[rloc * 136 + 64 + j] = f2bf(zb - bf2f(hb));
            acc_a = 0.f;
            acc_b = 0.f;
            rloc++;
            rCa = rNa;
            rCb = rNb;
            if (rloc + 1 < wend) {
                int nn = row0 + rloc + 1;
                if (nn < N_NODES) {
                    u32 rn = ub[(size_t)nn * 64 + j];
                    rNa = bfLo(rn); rNb = bfHi(rn);
                } else {
                    rNa = 0.f; rNb = 0.f;
                }
            }
            p1c = (rloc < wend) ? __builtin_amdgcn_readfirstlane(rp[rloc + 1]) : 0x7fffffff;
        };

#define LOAD_DESC(BASE, CC)                                                       \
        _Pragma("unroll")                                                         \
        for (int i_ = 0; i_ < 4; i_++) {                                          \
            int q_ = (BASE) + i_;                                                 \
            q_ = (q_ < pend) ? q_ : (pend - 1);                                   \
            CC##s[i_] = __builtin_amdgcn_readfirstlane(csr_src[q_]);              \
        }

#define ISSUE_DATA(BASE, CC, V, E0, E1)                                           \
        _Pragma("unroll")                                                         \
        for (int i_ = 0; i_ < 4; i_++) {                                          \
            V[i_] = ub[(size_t)CC##s[i_] * 64 + j];                               \
            int q_ = (BASE) + i_;                                                 \
            q_ = (q_ < pend) ? q_ : (pend - 1);                                   \
            E0[i_] = eap[(size_t)q_ * 2];                                         \
            E1[i_] = eap[(size_t)q_ * 2 + 1];                                     \
        }

#define COMPUTE_CHUNK(P, V, E0, E1)                                               \
        _Pragma("unroll")                                                         \
        for (int i_ = 0; i_ < 4; i_++) {                                          \
            int pos_ = (P) + i_;                                                  \
            if (pos_ < pend) {                                                    \
                while (pos_ >= p1c) flushRow();                                   \
                float ha_ = bfLo(V[i_]), hb_ = bfHi(V[i_]);                       \
                if (use_aff) {                                                    \
                    ha_ = fmaxf(fmaf(fA0, ha_, fB0), 0.f);                        \
                    hb_ = fmaxf(fmaf(fA1, hb_, fB1), 0.f);                        \
                }                                                                 \
                float eeA = bee0, eeB = bee1;                                     \
                eeA = fmaf(E0[i_].x, WeR[0], eeA);                                \
                eeB = fmaf(E0[i_].x, WeR[1], eeB);                                \
                eeA = fmaf(E0[i_].y, WeR[2], eeA);                                \
                eeB = fmaf(E0[i_].y, WeR[3], eeB);                                \
                eeA = fmaf(E0[i_].z, WeR[4], eeA);                                \
                eeB = fmaf(E0[i_].z, WeR[5], eeB);                                \
                eeA = fmaf(E0[i_].w, WeR[6], eeA);                                \
                eeB = fmaf(E0[i_].w, WeR[7], eeB);                                \
                eeA = fmaf(E1[i_].x, WeR[8], eeA);                                \
                eeB = fmaf(E1[i_].x, WeR[9], eeB);                                \
                eeA = fmaf(E1[i_].y, WeR[10], eeA);                               \
                eeB = fmaf(E1[i_].y, WeR[11], eeB);                               \
                eeA = fmaf(E1[i_].z, WeR[12], eeA);                               \
                eeB = fmaf(E1[i_].z, WeR[13], eeB);                               \
                eeA = fmaf(E1[i_].w, WeR[14], eeA);                               \
                eeB = fmaf(E1[i_].w, WeR[15], eeB);                               \
                acc_a += fmaxf(ha_ + eeA, 0.f);                                   \
                acc_b += fmaxf(hb_ + eeB, 0.f);                                   \
            }                                                                     \
        }

        if (pbeg < pend) {
            int cAs[4], cBs[4], cNs[4], cMs[4];
            u32 vA[4], vB[4];
            float4 eA0[4], eA1[4], eB0[4], eB1[4];

            LOAD_DESC(pbeg, cA)
            LOAD_DESC(pbeg + 4, cB)
            ISSUE_DATA(pbeg, cA, vA, eA0, eA1)
            ISSUE_DATA(pbeg + 4, cB, vB, eB0, eB1)
            LOAD_DESC(pbeg + 8, cN)
            for (int p = pbeg; p < pend; p += 8) {
                LOAD_DESC(p + 12, cM)
                COMPUTE_CHUNK(p, vA, eA0, eA1)
                ISSUE_DATA(p + 8, cN, vA, eA0, eA1)       // chunk p+8
                LOAD_DESC(p + 16, cN)
                COMPUTE_CHUNK(p + 4, vB, eB0, eB1)
                ISSUE_DATA(p + 12, cM, vB, eB0, eB1)      // chunk p+12
            }
        }
        while (rloc < wend) flushRow();   // tail (also covers empty / OOB rows)

#undef LOAD_DESC
#undef ISSUE_DATA
#undef COMPUTE_CHUNK
    }
    __syncthreads();

    // ---- MFMA: A (32 rows) from LDS hi/lo, B from pre-transposed bf16 global ----
    int wc = wave;                      // 4 waves x 64-col groups
    int m16 = lane & 15, kq = lane >> 4;
    f32x4 acc[2][4];
#pragma unroll
    for (int i = 0; i < 2; i++)
#pragma unroll
        for (int c = 0; c < 4; c++) acc[i][c] = (f32x4){0.f, 0.f, 0.f, 0.f};

#pragma unroll
    for (int ks = 0; ks < 4; ks++) {
        int k0 = ks * 32 + kq * 8;
        short8 Bf[4];
#pragma unroll
        for (int ct = 0; ct < 4; ct++)
            Bf[ct] = *(const short8*)(w1t + (size_t)(wc * 64 + ct * 16 + m16) * D + k0);
        short8 ah[2], al[2];
#pragma unroll
        for (int rt = 0; rt < 2; rt++) {
            ah[rt] = *(const short8*)(&Ah[(rt * 16 + m16) * 136 + k0]);
            al[rt] = *(const short8*)(&Al[(rt * 16 + m16) * 136 + k0]);
        }
#pragma unroll
        for (int rt = 0; rt < 2; rt++)
#pragma unroll
            for (int ct = 0; ct < 4; ct++) {
                acc[rt][ct] = __builtin_amdgcn_mfma_f32_16x16x32_bf16(ah[rt], Bf[ct],
                                                                     acc[rt][ct], 0, 0, 0);
                acc[rt][ct] = __builtin_amdgcn_mfma_f32_16x16x32_bf16(al[rt], Bf[ct],
                                                                     acc[rt][ct], 0, 0, 0);
            }
    }

    // ---- epilogue: bias, plain fp32 store to t (L3-resident), BN1 stats ----
#pragma unroll
    for (int ct = 0; ct < 4; ct++) {
        int col = wc * 64 + ct * 16 + m16;
        float bias = b1[col];
        float ls = 0.f, lq = 0.f;
#pragma unroll
        for (int rt = 0; rt < 2; rt++) {
#pragma unroll
            for (int rr = 0; rr < 4; rr++) {
                int row = row0 + rt * 16 + kq * 4 + rr;
                if (row < N_NODES) {
                    float v = acc[rt][ct][rr] + bias;
                    t[(size_t)row * TWO_D + col] = v;
                    ls += v;
                    lq += v * v;
                }
            }
        }
        atomicAdd(&sred[col], ls);
        atomicAdd(&sred[256 + col], lq);
    }
    __syncthreads();
    int slot = blockIdx.x & 7;
    atomicAdd(&s1[slot * TWO_D + tid], sred[tid]);
    atomicAdd(&s1sq[slot * TWO_D + tid], sred[256 + tid]);
}

// ---------------- GEMM2: ub = pack_bf16(relu(aff1(t)) @ W2 + b2), BN2 stats ----
// 256-thread / 64-row tiles: LDS ~21.5 KB -> 7 blocks/CU = 28 waves/CU.
// B from pre-transposed w2t global. Wave owns col-pair {c, c+64} -> packed u32 store.

__launch_bounds__(256, 4)
__global__ void gemm2_kernel(const float* __restrict__ t, const float* __restrict__ aff1a,
                             const float* __restrict__ aff1b, const u16* __restrict__ w2t,
                             const float* __restrict__ b2, u32* __restrict__ ub,
                             float* __restrict__ s2, float* __restrict__ s2sq) {
    __shared__ u16 CH[2 * 64 * 72];   // Ah, Al (64 rows x 72 each): 18.4 KB
    __shared__ float affL[512];
    __shared__ float sred[256];
    u16* AhC = CH;
    u16* AlC = CH + 64 * 72;

    int tid = threadIdx.x;
    int row0 = blockIdx.x * 64;
    affL[tid] = aff1a[tid];
    affL[256 + tid] = aff1b[tid];
    sred[tid] = 0.f;

    int lane = tid & 63, wave = tid >> 6;
    int wc = wave;                       // 4 waves x 16-col groups (pairs with +64)
    int m16 = lane & 15, kq = lane >> 4;
    f32x4 acc[4][2];
#pragma unroll
    for (int i = 0; i < 4; i++)
#pragma unroll
        for (int c = 0; c < 2; c++) acc[i][c] = (f32x4){0.f, 0.f, 0.f, 0.f};
    __syncthreads();

    for (int kc = 0; kc < 4; kc++) {
        // A staging: t fp32 [64 rows][64 k chunk] -> relu(aff1) -> hi/lo bf16
#pragma unroll
        for (int p = 0; p < 4; p++) {
            int idx = tid + p * 256;
            int row = idx >> 4, c4 = (idx & 15) * 4;
            f32x4 v = (f32x4){0.f, 0.f, 0.f, 0.f};
            if (row0 + row < N_NODES)
                v = *(const f32x4*)(t + (size_t)(row0 + row) * TWO_D + kc * 64 + c4);
            u16 hi4[4], lo4[4];
#pragma unroll
            for (int i = 0; i < 4; i++) {
                int k = kc * 64 + c4 + i;
                float g = fmaxf(fmaf(affL[k], v[i], affL[256 + k]), 0.f);
                u16 hi = f2bf(g);
                hi4[i] = hi;
                lo4[i] = f2bf(g - bf2f(hi));
            }
            *(uint2*)(&AhC[row * 72 + c4]) = *(const uint2*)hi4;
            *(uint2*)(&AlC[row * 72 + c4]) = *(const uint2*)lo4;
        }
        __syncthreads();
#pragma unroll
        for (int ks = 0; ks < 2; ks++) {
            int k0 = ks * 32 + kq * 8;
            short8 Bf[2];
#pragma unroll
            for (int ct = 0; ct < 2; ct++) {
                int col = ct * 64 + wc * 16 + m16;
                Bf[ct] = *(const short8*)(w2t + (size_t)col * TWO_D + kc * 64 + k0);
            }
            short8 ah[4], al[4];
#pragma unroll
            for (int rt = 0; rt < 4; rt++) {
                ah[rt] = *(const short8*)(&AhC[(rt * 16 + m16) * 72 + k0]);
                al[rt] = *(const short8*)(&AlC[(rt * 16 + m16) * 72 + k0]);
            }
#pragma unroll
            for (int rt = 0; rt < 4; rt++)
#pragma unroll
                for (int ct = 0; ct < 2; ct++) {
                    acc[rt][ct] = __builtin_amdgcn_mfma_f32_16x16x32_bf16(ah[rt], Bf[ct],
                                                                         acc[rt][ct], 0, 0, 0);
                    acc[rt][ct] = __builtin_amdgcn_mfma_f32_16x16x32_bf16(al[rt], Bf[ct],
                                                                         acc[rt][ct], 0, 0, 0);
                }
        }
        __syncthreads();   // A reads done before next chunk's A stage
    }

    // epilogue: bias, packed bf16-pair store to ub (cols c and c+64), BN2 stats
    {
        int c = wc * 16 + m16;               // low col; high col = c + 64
        float biasL = b2[c], biasH = b2[c + 64];
        float lsL = 0.f, lqL = 0.f, lsH = 0.f, lqH = 0.f;
#pragma unroll
        for (int rt = 0; rt < 4; rt++) {
#pragma unroll
            for (int rr = 0; rr < 4; rr++) {
                int row = row0 + rt * 16 + kq * 4 + rr;
                if (row < N_NODES) {
                    float vL = acc[rt][0][rr] + biasL;
                    float vH = acc[rt][1][rr] + biasH;
                    ub[(size_t)row * 64 + c] = packbf(vL, vH);
                    lsL += vL; lqL += vL * vL;
                    lsH += vH; lqH += vH * vH;
                }
            }
        }
        atomicAdd(&sred[c], lsL);
        atomicAdd(&sred[128 + c], lqL);
        atomicAdd(&sred[c + 64], lsH);
        atomicAdd(&sred[128 + c + 64], lqH);
    }
    __syncthreads();
    int slot = blockIdx.x & 7;
    if (tid < 128) atomicAdd(&s2[slot * D + tid], sred[tid]);
    else atomicAdd(&s2sq[slot * D + (tid - 128)], sred[tid]);
}

// ---------------- BN finalize ----------------

__global__ void finalize_kernel(const float* __restrict__ sums, const float* __restrict__ sumsq,
                                int ncols, const float* __restrict__ g,
                                const float* __restrict__ bt, float* __restrict__ affa,
                                float* __restrict__ affb) {
    int j = threadIdx.x;
    if (j < ncols) {
        float s = 0.f, q = 0.f;
        for (int k = 0; k < 8; k++) { s += sums[k * ncols + j]; q += sumsq[k * ncols + j]; }
        const float invN = 1.0f / (float)N_NODES;
        float mean = s * invN;
        float var = q * invN - mean * mean;
        float rstd = rsqrtf(var + BN_EPS);
        float a = g[j] * rstd;
        affa[j] = a;
        affb[j] = fmaf(-a, mean, bt[j]);
    }
}

// ---------------- final BN2 apply (no relu), packed ub -> out standard ----------------

__global__ void apply_final_kernel(const u32* __restrict__ ub, const float* __restrict__ a,
                                   const float* __restrict__ b, float* __restrict__ out) {
    const int total = N_NODES * 64;
    for (int idx = blockIdx.x * blockDim.x + threadIdx.x; idx < total;
         idx += gridDim.x * blockDim.x) {
        int n = idx >> 6, c = idx & 63;
        u32 v = ub[idx];
        out[(size_t)n * D + c] = fmaf(a[c], bfLo(v), b[c]);
        out[(size_t)n * D + 64 + c] = fmaf(a[64 + c], bfHi(v), b[64 + c]);
    }
}

// ---------------- launch ----------------

extern "C" void kernel_launch(void* const* d_in, const int* in_sizes, int n_in,
                              void* d_out, int out_size, void* d_ws, size_t ws_size,
                              hipStream_t stream) {
    (void)in_sizes; (void)n_in; (void)out_size; (void)ws_size;
    const float* x    = (const float*)d_in[0];
    const int*   ei   = (const int*)d_in[1];
    const float* ea   = (const float*)d_in[2];
    const float* Wn   = (const float*)d_in[3];
    const float* bn0  = (const float*)d_in[4];
    const float* We   = (const float*)d_in[5];
    const float* bee  = (const float*)d_in[6];
    const float* W1   = (const float*)d_in[7];
    const float* b1   = (const float*)d_in[8];
    const float* g1   = (const float*)d_in[9];
    const float* bt1  = (const float*)d_in[10];
    const float* W2   = (const float*)d_in[11];
    const float* b2   = (const float*)d_in[12];
    const float* eps  = (const float*)d_in[13];
    const float* gamma= (const float*)d_in[14];
    const float* beta = (const float*)d_in[15];
    float* out = (float*)d_out;

    // workspace layout, explicit byte offsets (total ~159.96 MB)
    char* ws = (char*)d_ws;
    u32*    ub    = (u32*)ws;                          // N*64 u32 packed bf16 pairs (25.6 MB)
    float4* eap   = (float4*)(ws + 25600000);          // E*32 B edge attrs in CSR order (19.2 MB)
    float*  t     = (float*)(ws + 51200000);           // N*256 fp32
    int*   rowptr = (int*)(ws + 153600000);            // N+1
    int*   deg    = (int*)(ws + 154000004);            // N  (reused for w2t after CSR build)
    int*   cursor = (int*)(ws + 154400004);            // N  (reused for wnh/wnl after scatter)
    int*   blocksum = (int*)(ws + 154800004);          // SCAN_NB+1
    int*   totalp = blocksum + SCAN_NB;
    int*   csr_src = (int*)(ws + 154801584);           // E ints (CSR-ordered src ids)
    float* stats  = (float*)(ws + 159601840);          // 6914 floats
    float* s1    = stats;            // [8][256]
    float* s1sq  = stats + 2048;     // [8][256]
    float* s2    = stats + 4096;     // [8][128]
    float* s2sq  = stats + 5120;     // [8][128]
    float* aff1a = stats + 6144;     // [256]
    float* aff1b = stats + 6400;     // [256]
    float* aff2a = stats + 6656;     // [128]
    float* aff2b = stats + 6784;     // [128]
    u16*   w1t   = (u16*)(ws + 159629504);             // [L][256][128] bf16
    u16*   w2t   = (u16*)(ws + 154000016);             // [L][128][256] bf16 (aliases dead deg)
    u16*   wnh   = (u16*)(ws + 154400016);             // [128][64] bf16 (aliases dead cursor)
    u16*   wnl   = (u16*)(ws + 154416400);             // [128][64] bf16

    const int* srcA = ei;
    const int* dstA = ei + N_EDGES;

    (void)hipMemsetAsync(deg, 0, N_NODES * sizeof(int), stream);
    hist_kernel<<<(N_EDGES + 255) / 256, 256, 0, stream>>>(dstA, deg);
    scan_partial_kernel<<<SCAN_NB, SCAN_B, 0, stream>>>(deg, blocksum);
    scan_blocks_kernel<<<1, 512, 0, stream>>>(blocksum, totalp);
    scan_apply_kernel<<<SCAN_NB, SCAN_B, 0, stream>>>(deg, blocksum, totalp, rowptr, cursor);
    scatter_kernel<<<(N_EDGES + 255) / 256, 256, 0, stream>>>(dstA, srcA, ea, cursor,
                                                              csr_src, eap);

    // after scatter, deg & cursor are dead -> prep writes w2t / wnh / wnl over them
    const int PREP_T = 2 * L_LAYERS * TWO_D * D + D * DIN;
    prep_w_kernel<<<(PREP_T + 255) / 256, 256, 0, stream>>>(W1, W2, Wn, w1t, w2t, wnh, wnl);
    encoder_kernel<<<(N_NODES + 63) / 64, 256, 0, stream>>>(x, wnh, wnl, bn0, ub);

    const int NB1 = (N_NODES + 31) / 32;    // 3125 (front, 32-row tiles)
    const int NB2 = (N_NODES + 63) / 64;    // 1563 (gemm2, 64-row tiles)
    for (int l = 0; l < L_LAYERS; l++) {
        (void)hipMemsetAsync(stats, 0, 6144 * sizeof(float), stream);
        front_kernel<<<NB1, 256, 0, stream>>>(
            ub, eap, rowptr, csr_src, We + (size_t)l * DE * D, bee + (size_t)l * D,
            eps, l, (l > 0) ? 1 : 0, aff2a, aff2b,
            w1t + (size_t)l * TWO_D * D, b1 + (size_t)l * TWO_D, t, s1, s1sq);
        finalize_kernel<<<1, 256, 0, stream>>>(s1, s1sq, TWO_D, g1 + (size_t)l * TWO_D,
                                               bt1 + (size_t)l * TWO_D, aff1a, aff1b);
        gemm2_kernel<<<NB2, 256, 0, stream>>>(
            t, aff1a, aff1b, w2t + (size_t)l * D * TWO_D, b2 + (size_t)l * D, ub, s2, s2sq);
        finalize_kernel<<<1, 128, 0, stream>>>(s2, s2sq, D, gamma + (size_t)l * D,
                                               beta + (size_t)l * D, aff2a, aff2b);
    }
    apply_final_kernel<<<4096, 256, 0, stream>>>(ub, aff2a, aff2b, out);
}

// Round 12
// 961.222 us; speedup vs baseline: 1.0230x; 1.0230x over previous
//
#include <hip/hip_runtime.h>
#include <hip/hip_bf16.h>

#define N_NODES 100000
#define N_EDGES 600000
#define DIN 64
#define DE 8
#define D 128
#define TWO_D 256
#define L_LAYERS 5
#define BN_EPS 1e-5f

#define SCAN_B 256
#define SCAN_NB ((N_NODES + SCAN_B - 1) / SCAN_B)   // 391

typedef unsigned short u16;
typedef unsigned int u32;
typedef __attribute__((ext_vector_type(8))) short short8;   // 8 bf16 MFMA A/B frag
typedef __attribute__((ext_vector_type(4))) float f32x4;    // MFMA C/D frag / native float4

__device__ inline u16 f2bf(float f) {
    __hip_bfloat16 h = __float2bfloat16(f);
    return *reinterpret_cast<u16*>(&h);
}
__device__ inline float bf2f(u16 u) {
    union { u32 i; float f; } v;
    v.i = ((u32)u) << 16;
    return v.f;
}
// packed pair {lo: h[c], hi: h[c+64]} in one u32
__device__ inline float bfLo(u32 v) {
    union { u32 i; float f; } u;
    u.i = v << 16;
    return u.f;
}
__device__ inline float bfHi(u32 v) {
    union { u32 i; float f; } u;
    u.i = v & 0xffff0000u;
    return u.f;
}
__device__ inline u32 packbf(float a, float b) {
    return (u32)f2bf(a) | ((u32)f2bf(b) << 16);
}

// ---------------- CSR build ----------------

__global__ void hist_kernel(const int* __restrict__ dst, int* __restrict__ deg) {
    int i = blockIdx.x * blockDim.x + threadIdx.x;
    if (i < N_EDGES) atomicAdd(&deg[dst[i]], 1);
}

__global__ void scan_partial_kernel(const int* __restrict__ deg, int* __restrict__ blocksum) {
    __shared__ int red[SCAN_B];
    int tid = threadIdx.x;
    int i = blockIdx.x * SCAN_B + tid;
    red[tid] = (i < N_NODES) ? deg[i] : 0;
    __syncthreads();
    for (int off = SCAN_B / 2; off > 0; off >>= 1) {
        if (tid < off) red[tid] += red[tid + off];
        __syncthreads();
    }
    if (tid == 0) blocksum[blockIdx.x] = red[0];
}

__global__ void scan_blocks_kernel(int* __restrict__ blocksum, int* __restrict__ total) {
    __shared__ int sh[512];
    int tid = threadIdx.x;
    int v = (tid < SCAN_NB) ? blocksum[tid] : 0;
    sh[tid] = v;
    __syncthreads();
    for (int off = 1; off < 512; off <<= 1) {
        int w = (tid >= off) ? sh[tid - off] : 0;
        __syncthreads();
        sh[tid] += w;
        __syncthreads();
    }
    if (tid < SCAN_NB) blocksum[tid] = sh[tid] - v;  // exclusive
    if (tid == 511) *total = sh[511];
}

__global__ void scan_apply_kernel(const int* __restrict__ deg, const int* __restrict__ blocksum,
                                  const int* __restrict__ total, int* __restrict__ rowptr,
                                  int* __restrict__ cursor) {
    __shared__ int sh[SCAN_B];
    int tid = threadIdx.x;
    int i = blockIdx.x * SCAN_B + tid;
    int v = (i < N_NODES) ? deg[i] : 0;
    sh[tid] = v;
    __syncthreads();
    for (int off = 1; off < SCAN_B; off <<= 1) {
        int w = (tid >= off) ? sh[tid - off] : 0;
        __syncthreads();
        sh[tid] += w;
        __syncthreads();
    }
    if (i < N_NODES) {
        int p = blocksum[blockIdx.x] + sh[tid] - v;  // exclusive prefix
        rowptr[i] = p;
        cursor[i] = p;
    }
    if (i == N_NODES - 1) rowptr[N_NODES] = *total;
}

// scatter: csr_src[p] = src  AND  ea_perm[p] = ea[edge]  (edge attrs in CSR order
// -> front's ea reads become sequential; only the ub gather stays random)
__global__ void scatter_kernel(const int* __restrict__ dst, const int* __restrict__ src,
                               const float* __restrict__ ea, int* __restrict__ cursor,
                               int* __restrict__ csr_src, float4* __restrict__ eap) {
    int i = blockIdx.x * blockDim.x + threadIdx.x;
    if (i < N_EDGES) {
        int d = dst[i];
        int p = atomicAdd(&cursor[d], 1);
        csr_src[p] = src[i];
        const float4* s = (const float4*)(ea + (size_t)i * DE);
        eap[(size_t)p * 2] = s[0];
        eap[(size_t)p * 2 + 1] = s[1];
    }
}

// ---------------- W pre-transpose ----------------
// w1t: fp32 [L][128][256] -> bf16 [L][256][128]   (GEMM1 B, [n][k])
// w2t: fp32 [L][256][128] -> bf16 [L][128][256]   (GEMM2 B, [n][k])
// wnh/wnl: fp32 [64][128] -> bf16 hi/lo [128][64] (encoder B, [n][k], split for ~fp32 acc)

__global__ void prep_w_kernel(const float* __restrict__ W1, const float* __restrict__ W2,
                              const float* __restrict__ Wn, u16* __restrict__ w1t,
                              u16* __restrict__ w2t, u16* __restrict__ wnh,
                              u16* __restrict__ wnl) {
    int idx = blockIdx.x * blockDim.x + threadIdx.x;
    const int T1 = L_LAYERS * TWO_D * D;   // 163840
    if (idx < T1) {
        int l = idx / (TWO_D * D);
        int rem = idx - l * (TWO_D * D);
        int n = rem >> 7;      // 0..255
        int k = rem & 127;     // 0..127
        w1t[idx] = f2bf(W1[((size_t)l * D + k) * TWO_D + n]);
    } else if (idx < 2 * T1) {
        int jdx = idx - T1;
        int l = jdx / (D * TWO_D);
        int rem = jdx - l * (D * TWO_D);
        int n = rem >> 8;      // 0..127
        int k = rem & 255;     // 0..255
        w2t[jdx] = f2bf(W2[((size_t)l * TWO_D + k) * D + n]);
    } else if (idx < 2 * T1 + D * DIN) {
        int r = idx - 2 * T1;
        int n = r >> 6;        // 0..127
        int k = r & 63;        // 0..63
        float v = Wn[(size_t)k * D + n];
        u16 hi = f2bf(v);
        wnh[r] = hi;
        wnl[r] = f2bf(v - bf2f(hi));
    }
}

// ---------------- node encoder (MFMA): ub = pack_bf16(x @ Wn + bn0) ----------------

__launch_bounds__(256, 4)
__global__ void encoder_kernel(const float* __restrict__ x, const u16* __restrict__ wnh,
                               const u16* __restrict__ wnl, const float* __restrict__ bn0,
                               u32* __restrict__ ub) {
    __shared__ __align__(16) u16 ENC[2 * 64 * 72];   // Ah, Al: 18.4 KB
    u16* Ah = ENC;
    u16* Al = ENC + 64 * 72;

    int tid = threadIdx.x;
    int row0 = blockIdx.x * 64;

    // stage x [64 rows][64 k] fp32 -> hi/lo bf16
#pragma unroll
    for (int p = 0; p < 4; p++) {
        int idx = tid + p * 256;
        int row = idx >> 4, c4 = (idx & 15) * 4;
        f32x4 v = (f32x4){0.f, 0.f, 0.f, 0.f};
        if (row0 + row < N_NODES)
            v = *(const f32x4*)(x + (size_t)(row0 + row) * DIN + c4);
        u16 hi4[4], lo4[4];
#pragma unroll
        for (int i = 0; i < 4; i++) {
            u16 hi = f2bf(v[i]);
            hi4[i] = hi;
            lo4[i] = f2bf(v[i] - bf2f(hi));
        }
        *(uint2*)(&Ah[row * 72 + c4]) = *(const uint2*)hi4;
        *(uint2*)(&Al[row * 72 + c4]) = *(const uint2*)lo4;
    }
    __syncthreads();

    int lane = tid & 63, wave = tid >> 6;
    int m16 = lane & 15, kq = lane >> 4;
    f32x4 acc[4][2];
#pragma unroll
    for (int i = 0; i < 4; i++)
#pragma unroll
        for (int c = 0; c < 2; c++) acc[i][c] = (f32x4){0.f, 0.f, 0.f, 0.f};

#pragma unroll
    for (int ks = 0; ks < 2; ks++) {
        int k0 = ks * 32 + kq * 8;
        short8 Bh[2], Bl[2];
#pragma unroll
        for (int ct = 0; ct < 2; ct++) {
            int col = ct * 64 + wave * 16 + m16;
            Bh[ct] = *(const short8*)(wnh + (size_t)col * DIN + k0);
            Bl[ct] = *(const short8*)(wnl + (size_t)col * DIN + k0);
        }
        short8 ah[4], al[4];
#pragma unroll
        for (int rt = 0; rt < 4; rt++) {
            ah[rt] = *(const short8*)(&Ah[(rt * 16 + m16) * 72 + k0]);
            al[rt] = *(const short8*)(&Al[(rt * 16 + m16) * 72 + k0]);
        }
#pragma unroll
        for (int rt = 0; rt < 4; rt++)
#pragma unroll
            for (int ct = 0; ct < 2; ct++) {
                acc[rt][ct] = __builtin_amdgcn_mfma_f32_16x16x32_bf16(ah[rt], Bh[ct],
                                                                     acc[rt][ct], 0, 0, 0);
                acc[rt][ct] = __builtin_amdgcn_mfma_f32_16x16x32_bf16(al[rt], Bh[ct],
                                                                     acc[rt][ct], 0, 0, 0);
                acc[rt][ct] = __builtin_amdgcn_mfma_f32_16x16x32_bf16(ah[rt], Bl[ct],
                                                                     acc[rt][ct], 0, 0, 0);
            }
    }

    // epilogue: bias, packed bf16-pair store (cols c and c+64)
    int c = wave * 16 + m16;
    float b0 = bn0[c], b1v = bn0[64 + c];
#pragma unroll
    for (int rt = 0; rt < 4; rt++) {
#pragma unroll
        for (int rr = 0; rr < 4; rr++) {
            int row = row0 + rt * 16 + kq * 4 + rr;
            if (row < N_NODES)
                ub[(size_t)row * 64 + c] = packbf(acc[rt][0][rr] + b0,
                                                  acc[rt][1][rr] + b1v);
        }
    }
}

// ---------------- front: fused [BN2-apply ∘ gather ∘ GEMM1] ----------------
// 256-thread / 32-row tiles: 4 waves x 8 rows. LDS ~19.6 KB.
// Explicit 6-stage modulo software pipeline: ub gather 3 chunks deep (v0/v1/v2),
// sequential ea 2 deep (e0/e1), scalar descriptors rotated 1 stage ahead (d0/d1).
// Static buffer names force the allocator to keep the pipeline live (R11: VGPR=48
// showed the compiler sank the 2-deep version's loads).

__launch_bounds__(256, 3)
__global__ void front_kernel(const u32* __restrict__ ub, const float4* __restrict__ eap,
                             const int* __restrict__ rowptr_g, const int* __restrict__ csr_src,
                             const float* __restrict__ We, const float* __restrict__ bee,
                             const float* __restrict__ epsArr, int layer, int use_aff,
                             const float* __restrict__ aff2a, const float* __restrict__ aff2b,
                             const u16* __restrict__ w1t, const float* __restrict__ b1,
                             float* __restrict__ t, float* __restrict__ s1,
                             float* __restrict__ s1sq) {
    __shared__ __align__(16) u16 UNI[2 * 32 * 136];   // Ah, Al (32 rows each): 17 KB
    __shared__ float sred[512];
    __shared__ int rp[36];

    u16* Ah = UNI;
    u16* Al = UNI + 32 * 136;

    int tid = threadIdx.x;
    int row0 = blockIdx.x * 32;

    if (tid < 33) {
        int g = row0 + tid;
        rp[tid] = rowptr_g[(g < N_NODES) ? g : N_NODES];
    }
    sred[tid] = 0.f;
    sred[256 + tid] = 0.f;
    __syncthreads();

    int lane = tid & 63, wave = tid >> 6;
    int j = lane;
    float epsv = 1.0f + epsArr[layer];

    // hoisted layer params (registers, loaded once; L2-hot)
    float WeR[16];   // WeR[2k] = We[k][j], WeR[2k+1] = We[k][j+64]
#pragma unroll
    for (int k = 0; k < 8; k++) {
        WeR[2 * k] = We[k * D + j];
        WeR[2 * k + 1] = We[k * D + 64 + j];
    }
    float bee0 = bee[j], bee1 = bee[64 + j];
    float fA0 = 0.f, fA1 = 0.f, fB0 = 0.f, fB1 = 0.f;
    if (use_aff) {
        fA0 = aff2a[j]; fA1 = aff2a[64 + j];
        fB0 = aff2b[j]; fB1 = aff2b[64 + j];
    }

    // ---- streaming gather: scalar control, 6-stage modulo pipeline ----
    {
        int wbeg = wave * 8, wend = wbeg + 8;
        int pbeg = __builtin_amdgcn_readfirstlane(rp[wbeg]);
        int pend = __builtin_amdgcn_readfirstlane(rp[wend]);
        int rloc = wbeg;
        int p1c = __builtin_amdgcn_readfirstlane(rp[wbeg + 1]);
        float acc_a = 0.f, acc_b = 0.f;
        float rCa = 0.f, rCb = 0.f, rNa = 0.f, rNb = 0.f;
        {
            int n0 = row0 + wbeg;
            if (n0 < N_NODES) {
                u32 r0 = ub[(size_t)n0 * 64 + j];
                rCa = bfLo(r0); rCb = bfHi(r0);
            }
            int n1 = n0 + 1;
            if (n1 < N_NODES) {
                u32 r1 = ub[(size_t)n1 * 64 + j];
                rNa = bfLo(r1); rNb = bfHi(r1);
            }
        }

        auto flushRow = [&]() {
            float oa = rCa, ob = rCb;
            if (use_aff) {
                oa = fmaxf(fmaf(fA0, oa, fB0), 0.f);
                ob = fmaxf(fmaf(fA1, ob, fB1), 0.f);
            }
            float za = fmaf(epsv, oa, acc_a);
            float zb = fmaf(epsv, ob, acc_b);
            u16 ha = f2bf(za), hb = f2bf(zb);
            Ah[rloc * 136 + j] = ha;
            Ah[rloc * 136 + 64 + j] = hb;
            Al[rloc * 136 + j] = f2bf(za - bf2f(ha));
            Al[rloc * 136 + 64 + j] = f2bf(zb - bf2f(hb));
            acc_a = 0.f;
            acc_b = 0.f;
            rloc++;
            rCa = rNa;
            rCb = rNb;
            if (rloc + 1 < wend) {
                int nn = row0 + rloc + 1;
                if (nn < N_NODES) {
                    u32 rn = ub[(size_t)nn * 64 + j];
                    rNa = bfLo(rn); rNb = bfHi(rn);
                } else {
                    rNa = 0.f; rNb = 0.f;
                }
            }
            p1c = (rloc < wend) ? __builtin_amdgcn_readfirstlane(rp[rloc + 1]) : 0x7fffffff;
        };

#define LOAD_DESC(BASE, DS)                                                       \
        _Pragma("unroll")                                                         \
        for (int i_ = 0; i_ < 4; i_++) {                                          \
            int q_ = (BASE) + i_;                                                 \
            q_ = (q_ < pend) ? q_ : (pend - 1);                                   \
            DS[i_] = __builtin_amdgcn_readfirstlane(csr_src[q_]);                 \
        }

#define UB_ISSUE(DS, V)                                                           \
        _Pragma("unroll")                                                         \
        for (int i_ = 0; i_ < 4; i_++) {                                          \
            V[i_] = ub[(size_t)DS[i_] * 64 + j];                                  \
        }

#define EA_ISSUE(BASE, EA_, EB_)                                                  \
        _Pragma("unroll")                                                         \
        for (int i_ = 0; i_ < 4; i_++) {                                          \
            int q_ = (BASE) + i_;                                                 \
            q_ = (q_ < pend) ? q_ : (pend - 1);                                   \
            EA_[i_] = eap[(size_t)q_ * 2];                                        \
            EB_[i_] = eap[(size_t)q_ * 2 + 1];                                    \
        }

#define COMPUTE_CHUNK(P, V, EA_, EB_)                                             \
        _Pragma("unroll")                                                         \
        for (int i_ = 0; i_ < 4; i_++) {                                          \
            int pos_ = (P) + i_;                                                  \
            if (pos_ < pend) {                                                    \
                while (pos_ >= p1c) flushRow();                                   \
                float ha_ = bfLo(V[i_]), hb_ = bfHi(V[i_]);                       \
                if (use_aff) {                                                    \
                    ha_ = fmaxf(fmaf(fA0, ha_, fB0), 0.f);                        \
                    hb_ = fmaxf(fmaf(fA1, hb_, fB1), 0.f);                        \
                }                                                                 \
                float eeA = bee0, eeB = bee1;                                     \
                eeA = fmaf(EA_[i_].x, WeR[0], eeA);                               \
                eeB = fmaf(EA_[i_].x, WeR[1], eeB);                               \
                eeA = fmaf(EA_[i_].y, WeR[2], eeA);                               \
                eeB = fmaf(EA_[i_].y, WeR[3], eeB);                               \
                eeA = fmaf(EA_[i_].z, WeR[4], eeA);                               \
                eeB = fmaf(EA_[i_].z, WeR[5], eeB);                               \
                eeA = fmaf(EA_[i_].w, WeR[6], eeA);                               \
                eeB = fmaf(EA_[i_].w, WeR[7], eeB);                               \
                eeA = fmaf(EB_[i_].x, WeR[8], eeA);                               \
                eeB = fmaf(EB_[i_].x, WeR[9], eeB);                               \
                eeA = fmaf(EB_[i_].y, WeR[10], eeA);                              \
                eeB = fmaf(EB_[i_].y, WeR[11], eeB);                              \
                eeA = fmaf(EB_[i_].z, WeR[12], eeA);                              \
                eeB = fmaf(EB_[i_].z, WeR[13], eeB);                              \
                eeA = fmaf(EB_[i_].w, WeR[14], eeA);                              \
                eeB = fmaf(EB_[i_].w, WeR[15], eeB);                              \
                acc_a += fmaxf(ha_ + eeA, 0.f);                                   \
                acc_b += fmaxf(hb_ + eeB, 0.f);                                   \
            }                                                                     \
        }

        if (pbeg < pend) {
            int d0s[4], d1s[4], dts[4];
            u32 v0[4], v1[4], v2[4];
            float4 e0A[4], e0B[4], e1A[4], e1B[4];

            // prologue: 3 ub chunks + 2 ea chunks in flight; descs 1 stage ahead
            LOAD_DESC(pbeg, dts)      UB_ISSUE(dts, v0)
            LOAD_DESC(pbeg + 4, dts)  UB_ISSUE(dts, v1)
            LOAD_DESC(pbeg + 8, dts)  UB_ISSUE(dts, v2)
            EA_ISSUE(pbeg, e0A, e0B)
            EA_ISSUE(pbeg + 4, e1A, e1B)
            LOAD_DESC(pbeg + 12, d0s)

            for (int p = pbeg; p < pend; p += 24) {
                // stage 0 (chunk p)
                COMPUTE_CHUNK(p, v0, e0A, e0B)
                UB_ISSUE(d0s, v0)                   // chunk p+12
                LOAD_DESC(p + 16, d1s)
                EA_ISSUE(p + 8, e0A, e0B)
                // stage 1 (p+4)
                COMPUTE_CHUNK(p + 4, v1, e1A, e1B)
                UB_ISSUE(d1s, v1)                   // p+16
                LOAD_DESC(p + 20, d0s)
                EA_ISSUE(p + 12, e1A, e1B)
                // stage 2 (p+8)
                COMPUTE_CHUNK(p + 8, v2, e0A, e0B)
                UB_ISSUE(d0s, v2)                   // p+20
                LOAD_DESC(p + 24, d1s)
                EA_ISSUE(p + 16, e0A, e0B)
                // stage 3 (p+12)
                COMPUTE_CHUNK(p + 12, v0, e1A, e1B)
                UB_ISSUE(d1s, v0)                   // p+24
                LOAD_DESC(p + 28, d0s)
                EA_ISSUE(p + 20, e1A, e1B)
                // stage 4 (p+16)
                COMPUTE_CHUNK(p + 16, v1, e0A, e0B)
                UB_ISSUE(d0s, v1)                   // p+28
                LOAD_DESC(p + 32, d1s)
                EA_ISSUE(p + 24, e0A, e0B)
                // stage 5 (p+20)
                COMPUTE_CHUNK(p + 20, v2, e1A, e1B)
                UB_ISSUE(d1s, v2)                   // p+32
                LOAD_DESC(p + 36, d0s)
                EA_ISSUE(p + 28, e1A, e1B)
            }
        }
        while (rloc < wend) flushRow();   // tail (also covers empty / OOB rows)

#undef LOAD_DESC
#undef UB_ISSUE
#undef EA_ISSUE
#undef COMPUTE_CHUNK
    }
    __syncthreads();

    // ---- MFMA: A (32 rows) from LDS hi/lo, B from pre-transposed bf16 global ----
    int wc = wave;                      // 4 waves x 64-col groups
    int m16 = lane & 15, kq = lane >> 4;
    f32x4 acc[2][4];
#pragma unroll
    for (int i = 0; i < 2; i++)
#pragma unroll
        for (int c = 0; c < 4; c++) acc[i][c] = (f32x4){0.f, 0.f, 0.f, 0.f};

#pragma unroll
    for (int ks = 0; ks < 4; ks++) {
        int k0 = ks * 32 + kq * 8;
        short8 Bf[4];
#pragma unroll
        for (int ct = 0; ct < 4; ct++)
            Bf[ct] = *(const short8*)(w1t + (size_t)(wc * 64 + ct * 16 + m16) * D + k0);
        short8 ah[2], al[2];
#pragma unroll
        for (int rt = 0; rt < 2; rt++) {
            ah[rt] = *(const short8*)(&Ah[(rt * 16 + m16) * 136 + k0]);
            al[rt] = *(const short8*)(&Al[(rt * 16 + m16) * 136 + k0]);
        }
#pragma unroll
        for (int rt = 0; rt < 2; rt++)
#pragma unroll
            for (int ct = 0; ct < 4; ct++) {
                acc[rt][ct] = __builtin_amdgcn_mfma_f32_16x16x32_bf16(ah[rt], Bf[ct],
                                                                     acc[rt][ct], 0, 0, 0);
                acc[rt][ct] = __builtin_amdgcn_mfma_f32_16x16x32_bf16(al[rt], Bf[ct],
                                                                     acc[rt][ct], 0, 0, 0);
            }
    }

    // ---- epilogue: bias, plain fp32 store to t (L3-resident), BN1 stats ----
#pragma unroll
    for (int ct = 0; ct < 4; ct++) {
        int col = wc * 64 + ct * 16 + m16;
        float bias = b1[col];
        float ls = 0.f, lq = 0.f;
#pragma unroll
        for (int rt = 0; rt < 2; rt++) {
#pragma unroll
            for (int rr = 0; rr < 4; rr++) {
                int row = row0 + rt * 16 + kq * 4 + rr;
                if (row < N_NODES) {
                    float v = acc[rt][ct][rr] + bias;
                    t[(size_t)row * TWO_D + col] = v;
                    ls += v;
                    lq += v * v;
                }
            }
        }
        atomicAdd(&sred[col], ls);
        atomicAdd(&sred[256 + col], lq);
    }
    __syncthreads();
    int slot = blockIdx.x & 7;
    atomicAdd(&s1[slot * TWO_D + tid], sred[tid]);
    atomicAdd(&s1sq[slot * TWO_D + tid], sred[256 + tid]);
}

// ---------------- GEMM2: ub = pack_bf16(relu(aff1(t)) @ W2 + b2), BN2 stats ----
// 256-thread / 64-row tiles: LDS ~21.5 KB -> 7 blocks/CU = 28 waves/CU.
// B from pre-transposed w2t global. Wave owns col-pair {c, c+64} -> packed u32 store.

__launch_bounds__(256, 4)
__global__ void gemm2_kernel(const float* __restrict__ t, const float* __restrict__ aff1a,
                             const float* __restrict__ aff1b, const u16* __restrict__ w2t,
                             const float* __restrict__ b2, u32* __restrict__ ub,
                             float* __restrict__ s2, float* __restrict__ s2sq) {
    __shared__ u16 CH[2 * 64 * 72];   // Ah, Al (64 rows x 72 each): 18.4 KB
    __shared__ float affL[512];
    __shared__ float sred[256];
    u16* AhC = CH;
    u16* AlC = CH + 64 * 72;

    int tid = threadIdx.x;
    int row0 = blockIdx.x * 64;
    affL[tid] = aff1a[tid];
    affL[256 + tid] = aff1b[tid];
    sred[tid] = 0.f;

    int lane = tid & 63, wave = tid >> 6;
    int wc = wave;                       // 4 waves x 16-col groups (pairs with +64)
    int m16 = lane & 15, kq = lane >> 4;
    f32x4 acc[4][2];
#pragma unroll
    for (int i = 0; i < 4; i++)
#pragma unroll
        for (int c = 0; c < 2; c++) acc[i][c] = (f32x4){0.f, 0.f, 0.f, 0.f};
    __syncthreads();

    for (int kc = 0; kc < 4; kc++) {
        // A staging: t fp32 [64 rows][64 k chunk] -> relu(aff1) -> hi/lo bf16
#pragma unroll
        for (int p = 0; p < 4; p++) {
            int idx = tid + p * 256;
            int row = idx >> 4, c4 = (idx & 15) * 4;
            f32x4 v = (f32x4){0.f, 0.f, 0.f, 0.f};
            if (row0 + row < N_NODES)
                v = *(const f32x4*)(t + (size_t)(row0 + row) * TWO_D + kc * 64 + c4);
            u16 hi4[4], lo4[4];
#pragma unroll
            for (int i = 0; i < 4; i++) {
                int k = kc * 64 + c4 + i;
                float g = fmaxf(fmaf(affL[k], v[i], affL[256 + k]), 0.f);
                u16 hi = f2bf(g);
                hi4[i] = hi;
                lo4[i] = f2bf(g - bf2f(hi));
            }
            *(uint2*)(&AhC[row * 72 + c4]) = *(const uint2*)hi4;
            *(uint2*)(&AlC[row * 72 + c4]) = *(const uint2*)lo4;
        }
        __syncthreads();
#pragma unroll
        for (int ks = 0; ks < 2; ks++) {
            int k0 = ks * 32 + kq * 8;
            short8 Bf[2];
#pragma unroll
            for (int ct = 0; ct < 2; ct++) {
                int col = ct * 64 + wc * 16 + m16;
                Bf[ct] = *(const short8*)(w2t + (size_t)col * TWO_D + kc * 64 + k0);
            }
            short8 ah[4], al[4];
#pragma unroll
            for (int rt = 0; rt < 4; rt++) {
                ah[rt] = *(const short8*)(&AhC[(rt * 16 + m16) * 72 + k0]);
                al[rt] = *(const short8*)(&AlC[(rt * 16 + m16) * 72 + k0]);
            }
#pragma unroll
            for (int rt = 0; rt < 4; rt++)
#pragma unroll
                for (int ct = 0; ct < 2; ct++) {
                    acc[rt][ct] = __builtin_amdgcn_mfma_f32_16x16x32_bf16(ah[rt], Bf[ct],
                                                                         acc[rt][ct], 0, 0, 0);
                    acc[rt][ct] = __builtin_amdgcn_mfma_f32_16x16x32_bf16(al[rt], Bf[ct],
                                                                         acc[rt][ct], 0, 0, 0);
                }
        }
        __syncthreads();   // A reads done before next chunk's A stage
    }

    // epilogue: bias, packed bf16-pair store to ub (cols c and c+64), BN2 stats
    {
        int c = wc * 16 + m16;               // low col; high col = c + 64
        float biasL = b2[c], biasH = b2[c + 64];
        float lsL = 0.f, lqL = 0.f, lsH = 0.f, lqH = 0.f;
#pragma unroll
        for (int rt = 0; rt < 4; rt++) {
#pragma unroll
            for (int rr = 0; rr < 4; rr++) {
                int row = row0 + rt * 16 + kq * 4 + rr;
                if (row < N_NODES) {
                    float vL = acc[rt][0][rr] + biasL;
                    float vH = acc[rt][1][rr] + biasH;
                    ub[(size_t)row * 64 + c] = packbf(vL, vH);
                    lsL += vL; lqL += vL * vL;
                    lsH += vH; lqH += vH * vH;
                }
            }
        }
        atomicAdd(&sred[c], lsL);
        atomicAdd(&sred[128 + c], lqL);
        atomicAdd(&sred[c + 64], lsH);
        atomicAdd(&sred[128 + c + 64], lqH);
    }
    __syncthreads();
    int slot = blockIdx.x & 7;
    if (tid < 128) atomicAdd(&s2[slot * D + tid], sred[tid]);
    else atomicAdd(&s2sq[slot * D + (tid - 128)], sred[tid]);
}

// ---------------- BN finalize ----------------

__global__ void finalize_kernel(const float* __restrict__ sums, const float* __restrict__ sumsq,
                                int ncols, const float* __restrict__ g,
                                const float* __restrict__ bt, float* __restrict__ affa,
                                float* __restrict__ affb) {
    int j = threadIdx.x;
    if (j < ncols) {
        float s = 0.f, q = 0.f;
        for (int k = 0; k < 8; k++) { s += sums[k * ncols + j]; q += sumsq[k * ncols + j]; }
        const float invN = 1.0f / (float)N_NODES;
        float mean = s * invN;
        float var = q * invN - mean * mean;
        float rstd = rsqrtf(var + BN_EPS);
        float a = g[j] * rstd;
        affa[j] = a;
        affb[j] = fmaf(-a, mean, bt[j]);
    }
}

// ---------------- final BN2 apply (no relu), packed ub -> out standard ----------------

__global__ void apply_final_kernel(const u32* __restrict__ ub, const float* __restrict__ a,
                                   const float* __restrict__ b, float* __restrict__ out) {
    const int total = N_NODES * 64;
    for (int idx = blockIdx.x * blockDim.x + threadIdx.x; idx < total;
         idx += gridDim.x * blockDim.x) {
        int n = idx >> 6, c = idx & 63;
        u32 v = ub[idx];
        out[(size_t)n * D + c] = fmaf(a[c], bfLo(v), b[c]);
        out[(size_t)n * D + 64 + c] = fmaf(a[64 + c], bfHi(v), b[64 + c]);
    }
}

// ---------------- launch ----------------

extern "C" void kernel_launch(void* const* d_in, const int* in_sizes, int n_in,
                              void* d_out, int out_size, void* d_ws, size_t ws_size,
                              hipStream_t stream) {
    (void)in_sizes; (void)n_in; (void)out_size; (void)ws_size;
    const float* x    = (const float*)d_in[0];
    const int*   ei   = (const int*)d_in[1];
    const float* ea   = (const float*)d_in[2];
    const float* Wn   = (const float*)d_in[3];
    const float* bn0  = (const float*)d_in[4];
    const float* We   = (const float*)d_in[5];
    const float* bee  = (const float*)d_in[6];
    const float* W1   = (const float*)d_in[7];
    const float* b1   = (const float*)d_in[8];
    const float* g1   = (const float*)d_in[9];
    const float* bt1  = (const float*)d_in[10];
    const float* W2   = (const float*)d_in[11];
    const float* b2   = (const float*)d_in[12];
    const float* eps  = (const float*)d_in[13];
    const float* gamma= (const float*)d_in[14];
    const float* beta = (const float*)d_in[15];
    float* out = (float*)d_out;

    // workspace layout, explicit byte offsets (total ~159.96 MB)
    char* ws = (char*)d_ws;
    u32*    ub    = (u32*)ws;                          // N*64 u32 packed bf16 pairs (25.6 MB)
    float4* eap   = (float4*)(ws + 25600000);          // E*32 B edge attrs in CSR order (19.2 MB)
    float*  t     = (float*)(ws + 51200000);           // N*256 fp32
    int*   rowptr = (int*)(ws + 153600000);            // N+1
    int*   deg    = (int*)(ws + 154000004);            // N  (reused for w2t after CSR build)
    int*   cursor = (int*)(ws + 154400004);            // N  (reused for wnh/wnl after scatter)
    int*   blocksum = (int*)(ws + 154800004);          // SCAN_NB+1
    int*   totalp = blocksum + SCAN_NB;
    int*   csr_src = (int*)(ws + 154801584);           // E ints (CSR-ordered src ids)
    float* stats  = (float*)(ws + 159601840);          // 6914 floats
    float* s1    = stats;            // [8][256]
    float* s1sq  = stats + 2048;     // [8][256]
    float* s2    = stats + 4096;     // [8][128]
    float* s2sq  = stats + 5120;     // [8][128]
    float* aff1a = stats + 6144;     // [256]
    float* aff1b = stats + 6400;     // [256]
    float* aff2a = stats + 6656;     // [128]
    float* aff2b = stats + 6784;     // [128]
    u16*   w1t   = (u16*)(ws + 159629504);             // [L][256][128] bf16
    u16*   w2t   = (u16*)(ws + 154000016);             // [L][128][256] bf16 (aliases dead deg)
    u16*   wnh   = (u16*)(ws + 154400016);             // [128][64] bf16 (aliases dead cursor)
    u16*   wnl   = (u16*)(ws + 154416400);             // [128][64] bf16

    const int* srcA = ei;
    const int* dstA = ei + N_EDGES;

    (void)hipMemsetAsync(deg, 0, N_NODES * sizeof(int), stream);
    hist_kernel<<<(N_EDGES + 255) / 256, 256, 0, stream>>>(dstA, deg);
    scan_partial_kernel<<<SCAN_NB, SCAN_B, 0, stream>>>(deg, blocksum);
    scan_blocks_kernel<<<1, 512, 0, stream>>>(blocksum, totalp);
    scan_apply_kernel<<<SCAN_NB, SCAN_B, 0, stream>>>(deg, blocksum, totalp, rowptr, cursor);
    scatter_kernel<<<(N_EDGES + 255) / 256, 256, 0, stream>>>(dstA, srcA, ea, cursor,
                                                              csr_src, eap);

    // after scatter, deg & cursor are dead -> prep writes w2t / wnh / wnl over them
    const int PREP_T = 2 * L_LAYERS * TWO_D * D + D * DIN;
    prep_w_kernel<<<(PREP_T + 255) / 256, 256, 0, stream>>>(W1, W2, Wn, w1t, w2t, wnh, wnl);
    encoder_kernel<<<(N_NODES + 63) / 64, 256, 0, stream>>>(x, wnh, wnl, bn0, ub);

    const int NB1 = (N_NODES + 31) / 32;    // 3125 (front, 32-row tiles)
    const int NB2 = (N_NODES + 63) / 64;    // 1563 (gemm2, 64-row tiles)
    for (int l = 0; l < L_LAYERS; l++) {
        (void)hipMemsetAsync(stats, 0, 6144 * sizeof(float), stream);
        front_kernel<<<NB1, 256, 0, stream>>>(
            ub, eap, rowptr, csr_src, We + (size_t)l * DE * D, bee + (size_t)l * D,
            eps, l, (l > 0) ? 1 : 0, aff2a, aff2b,
            w1t + (size_t)l * TWO_D * D, b1 + (size_t)l * TWO_D, t, s1, s1sq);
        finalize_kernel<<<1, 256, 0, stream>>>(s1, s1sq, TWO_D, g1 + (size_t)l * TWO_D,
                                               bt1 + (size_t)l * TWO_D, aff1a, aff1b);
        gemm2_kernel<<<NB2, 256, 0, stream>>>(
            t, aff1a, aff1b, w2t + (size_t)l * D * TWO_D, b2 + (size_t)l * D, ub, s2, s2sq);
        finalize_kernel<<<1, 128, 0, stream>>>(s2, s2sq, D, gamma + (size_t)l * D,
                                               beta + (size_t)l * D, aff2a, aff2b);
    }
    apply_final_kernel<<<4096, 256, 0, stream>>>(ub, aff2a, aff2b, out);
}